// Round 10
// baseline (159.270 us; speedup 1.0000x reference)
//
#include <hip/hip_runtime.h>
#include <hip/hip_bf16.h>

// Problem constants: B=2, N=2048, D=512, H=8, hd=64
typedef __bf16 bf16x8 __attribute__((ext_vector_type(8)));
typedef float f32x4 __attribute__((ext_vector_type(4)));
typedef unsigned short u16x8 __attribute__((ext_vector_type(8)));

#define LOG2E 1.44269504f

__device__ __forceinline__ unsigned short f2bu(float f) {
    __hip_bfloat16 h = __float2bfloat16(f);
    unsigned short u;
    __builtin_memcpy(&u, &h, 2);
    return u;
}

__device__ __forceinline__ float fexp2(float x) {
#if __has_builtin(__builtin_amdgcn_exp2f)
    return __builtin_amdgcn_exp2f(x);
#else
    return __expf(x * 0.69314718f);
#endif
}

__device__ __forceinline__ float bu2f(unsigned short u) {
    unsigned int v = ((unsigned int)u) << 16;
    float f;
    __builtin_memcpy(&f, &v, 4);
    return f;
}

// async global->LDS, 16B per lane. LDS base must be wave-uniform; HW appends lane*16.
#define GLDS16(gp, lp) __builtin_amdgcn_global_load_lds( \
    (const __attribute__((address_space(1))) unsigned int*)(gp), \
    (__attribute__((address_space(3))) unsigned int*)(lp), 16, 0, 0)

// ---- workspace layout (bytes) ----
#define OFF_QS  0u                          // Q*(0.125*log2e) bf16  4 MB
#define OFF_KB  4194304u                    // K bf16                4 MB
#define OFF_VT  8388608u                    // V^T [b,h,d,n] bf16    4 MB
#define OFF_CV  12582912u                   // cv2[b,n] f32 = 2^((c-8)*log2e)  16 KB
#define OFF_XB  12599296u                   // x bf16                4 MB
#define OFF_WT  16793600u                   // W^T bf16              1.5 MB
#define OFF_MQ  18366464u                   // m transposed-perm bf16 16.78 MB
#define OFF_PO  35143680u                   // partial O bf16, 8192 chunks x 1024  16.78 MB
#define OFF_PL  51920896u                   // partial lsum f32, 8192 chunks x 16  512 KB

// ---------------- prep (merged): x->bf16 + cv2, and Wt[n][k] = bf16(W[k][n]) ----------------
__global__ void k_prepwt(const float* __restrict__ x, const float* __restrict__ wg,
                         const float* __restrict__ w0, const float* __restrict__ w1,
                         const float* __restrict__ w2,
                         unsigned short* __restrict__ xb, float* __restrict__ cv2,
                         unsigned short* __restrict__ wt) {
    if (blockIdx.x < 1024) {
        int row = blockIdx.x * 4 + (threadIdx.x >> 6);   // 4096 rows
        int l = threadIdx.x & 63;
        const float4* xr = reinterpret_cast<const float4*>(x + (size_t)row * 512);
        float4 a = xr[l * 2], b2 = xr[l * 2 + 1];
        ushort4 o0, o1;
        o0.x = f2bu(a.x);  o0.y = f2bu(a.y);  o0.z = f2bu(a.z);  o0.w = f2bu(a.w);
        o1.x = f2bu(b2.x); o1.y = f2bu(b2.y); o1.z = f2bu(b2.z); o1.w = f2bu(b2.w);
        ushort4* dst = reinterpret_cast<ushort4*>(xb + (size_t)row * 512);
        dst[l * 2] = o0; dst[l * 2 + 1] = o1;
        const float4* wr = reinterpret_cast<const float4*>(wg + 512);
        float4 g0 = wr[l * 2], g1 = wr[l * 2 + 1];
        float s = a.x * g0.x + a.y * g0.y + a.z * g0.z + a.w * g0.w
                + b2.x * g1.x + b2.y * g1.y + b2.z * g1.z + b2.w * g1.w;
#pragma unroll
        for (int off = 32; off >= 1; off >>= 1) s += __shfl_xor(s, off, 64);
        if (l == 0) cv2[row] = fexp2((s - 8.0f) * LOG2E);
    } else {
        int bid2 = blockIdx.x - 1024;        // 192 blocks: z*64 + yy
        int z = bid2 >> 6, yy = bid2 & 63;
        int k0 = (yy >> 3) * 64, n0 = (yy & 7) * 64;
        const float* W = (z == 0) ? w0 : ((z == 1) ? w1 : w2);
        __shared__ float T[64][65];
        int c = threadIdx.x & 63, r0 = threadIdx.x >> 6;
#pragma unroll
        for (int i = 0; i < 16; i++) { int r = r0 + i * 4; T[r][c] = W[(k0 + r) * 512 + n0 + c]; }
        __syncthreads();
        unsigned short* Wt = wt + z * (512 * 512);
#pragma unroll
        for (int i = 0; i < 16; i++) { int a = r0 + i * 4; Wt[(n0 + a) * 512 + k0 + c] = f2bu(T[c][a]); }
    }
}

// ---------------- merged: adjp (transposed perm) + QKV GEMM ----------------
// adjp (blocks 0..8191): mq[((b*128+ic)*32+jt)*1024 + l*16 + mt*4 + r]
//   = bf16((adj[b][ic*16+cl][j] + eps) * cv2[b][j]),  j = jt*64 + 16*mt + q*4 + r, l=q*16+cl.
// gemm (blocks 8192..8959): 64x128 tile QKV projection; z==2 writes V^T directly.
__global__ __launch_bounds__(256) void k_mid(
    const float* __restrict__ adj, const float* __restrict__ cv2,
    unsigned short* __restrict__ mq,
    const unsigned short* __restrict__ xb, const unsigned short* __restrict__ wt,
    const float* __restrict__ bq, const float* __restrict__ bk, const float* __restrict__ bv,
    unsigned short* __restrict__ Qs, unsigned short* __restrict__ Kb,
    unsigned short* __restrict__ Vt) {
    if (blockIdx.x < 8192) {
        int blk = blockIdx.x;              // bic*32 + jt
        int bic = blk >> 5, jt = blk & 31;
        int b = bic >> 7, ic = bic & 127;
        int t = threadIdx.x;               // t = l*4 + mt
        int l = t >> 2, mt = t & 3, q = l >> 4, cl = l & 15;
        int j0 = jt * 64 + 16 * mt + q * 4;
        const float4 av = *reinterpret_cast<const float4*>(
            adj + ((size_t)(b * 2048 + ic * 16 + cl)) * 2048 + j0);
        const float4 cv = *reinterpret_cast<const float4*>(cv2 + b * 2048 + j0);
        ushort4 o;
        o.x = f2bu((av.x + 1e-9f) * cv.x);
        o.y = f2bu((av.y + 1e-9f) * cv.y);
        o.z = f2bu((av.z + 1e-9f) * cv.z);
        o.w = f2bu((av.w + 1e-9f) * cv.w);
        *reinterpret_cast<ushort4*>(mq + (size_t)bic * 32768 + jt * 1024 + l * 16 + mt * 4) = o;
        return;
    }
    int gid = blockIdx.x - 8192;           // 768: x(64) y(4) z(3)
    int bx = gid & 63, by = (gid >> 6) & 3, z = gid >> 8;
    __shared__ __align__(16) unsigned short As[64 * 32];
    __shared__ __align__(16) unsigned short Bs[128 * 32];
    const unsigned short* Wt = wt + z * (512 * 512);
    const float* bias = (z == 0) ? bq : ((z == 1) ? bk : bv);
    float scale = (z == 0) ? (0.125f * LOG2E) : 1.0f;   // Q pre-scaled by log2e/sqrt(64)
    int m0 = bx * 64, n0 = by * 128;
    int tid = threadIdx.x, w = tid >> 6, l = tid & 63;
    int q = l >> 4, cl = l & 15;
    f32x4 acc[8];
#pragma unroll
    for (int nt = 0; nt < 8; nt++)
#pragma unroll
        for (int r = 0; r < 4; r++) acc[nt][r] = 0.f;
    int arow = l >> 2, ach = (l & 3) * 8;
    for (int k0 = 0; k0 < 512; k0 += 32) {
        GLDS16(xb + (size_t)(m0 + w * 16 + arow) * 512 + k0 + ach, As + w * 512);
#pragma unroll
        for (int e = 0; e < 2; e++)
            GLDS16(Wt + (size_t)(n0 + w * 32 + e * 16 + arow) * 512 + k0 + ach, Bs + w * 1024 + e * 512);
        __syncthreads();
        bf16x8 af = *reinterpret_cast<const bf16x8*>(As + (w * 16 + cl) * 32 + q * 8);
#pragma unroll
        for (int nt = 0; nt < 8; nt++) {
            bf16x8 bf = *reinterpret_cast<const bf16x8*>(Bs + (nt * 16 + cl) * 32 + q * 8);
            acc[nt] = __builtin_amdgcn_mfma_f32_16x16x32_bf16(af, bf, acc[nt], 0, 0, 0);
        }
        __syncthreads();
    }
    if (z == 2) {
        int n_ = (m0 + w * 16 + q * 4) & 2047;
        int b_ = (m0 + w * 16) >> 11;
#pragma unroll
        for (int nt = 0; nt < 8; nt++) {
            int col = n0 + nt * 16 + cl;
            int h_ = col >> 6, d_ = col & 63;
            float bv_ = bias[col];
            ushort4 o;
            o.x = f2bu(acc[nt][0] + bv_); o.y = f2bu(acc[nt][1] + bv_);
            o.z = f2bu(acc[nt][2] + bv_); o.w = f2bu(acc[nt][3] + bv_);
            *reinterpret_cast<ushort4*>(Vt + ((size_t)((b_ * 8 + h_) * 64 + d_)) * 2048 + n_) = o;
        }
    } else {
        unsigned short* Cout = (z == 0) ? Qs : Kb;
#pragma unroll
        for (int nt = 0; nt < 8; nt++) {
            int col = n0 + nt * 16 + cl;
            float bv_ = bias[col];
#pragma unroll
            for (int r = 0; r < 4; r++) {
                int row = m0 + w * 16 + q * 4 + r;
                Cout[(size_t)row * 512 + col] = f2bu((acc[nt][r] + bv_) * scale);
            }
        }
    }
}

// ---------------- flash attention: transposed-S, SINGLE-buffered LDS, 4 blocks/CU ----------------
// 1024 blocks x 256 thr. Dbuf proven neutral (r7/r9 vs r6) -> spend LDS on occupancy instead:
// Ks+Vs+PA = 34.8 KB -> 4 blocks/CU (16 waves/CU); other blocks' compute hides this block's
// barrier/vmcnt drains. bid = h*128 + b*64 + ig*4 + js (h-siblings share XCD for mq L2 reuse).
// Wave w: rows [ig*128 + w*32, +32) as 2 chunks rc; j-range [js*512,+512) = 8 tiles of 64.
// Per iter: stage tile t; barrier (drains GLDS16+m loads); compute; barrier.
__global__ __launch_bounds__(256, 4) void k_attn(
    const unsigned short* __restrict__ Qs, const unsigned short* __restrict__ Kb,
    const unsigned short* __restrict__ Vt, const unsigned short* __restrict__ mq,
    unsigned short* __restrict__ PO, float* __restrict__ PL) {
    __shared__ __align__(16) unsigned short Ks[4096];        // [kk][64 j][32 d]
    __shared__ __align__(16) unsigned short Vs[4096];        // [jc][64 d][32 j]
    __shared__ __align__(16) unsigned short PA[4][32 * 72];  // per-wave P[i][j] (2 rc), stride 72
    int bid = blockIdx.x;
    int h = bid >> 7, b = (bid >> 6) & 1, ig = (bid >> 2) & 15, js = bid & 3;
    int tid = threadIdx.x, w = tid >> 6, l = tid & 63, q = l >> 4, cl = l & 15;
    int bh = b * 8 + h;
    int ic0 = ig * 8 + w * 2;

    // Q^T B-fragments for 2 row-chunks, loop-invariant
    bf16x8 qf[2][2];
#pragma unroll
    for (int rc = 0; rc < 2; rc++) {
        const unsigned short* qp = Qs + (size_t)(b * 2048 + ig * 128 + w * 32 + rc * 16 + cl) * 512 + h * 64 + q * 8;
        qf[rc][0] = *reinterpret_cast<const bf16x8*>(qp);
        qf[rc][1] = *reinterpret_cast<const bf16x8*>(qp + 32);
    }
    bf16x8 ones;
#pragma unroll
    for (int i = 0; i < 8; i++) { unsigned short o1 = 0x3F80; __builtin_memcpy(((unsigned short*)&ones) + i, &o1, 2); }

    f32x4 O[2][4];
    f32x4 Osum[2];
#pragma unroll
    for (int rc = 0; rc < 2; rc++) {
#pragma unroll
        for (int nt = 0; nt < 4; nt++)
#pragma unroll
            for (int r = 0; r < 4; r++) O[rc][nt][r] = 0.f;
#pragma unroll
        for (int r = 0; r < 4; r++) Osum[rc][r] = 0.f;
    }

    const unsigned short* Kh = Kb + (size_t)b * 2048 * 512 + h * 64;
    const unsigned short* Vh = Vt + ((size_t)bh * 64) * 2048;
    const unsigned short* mb0 = mq + (size_t)(b * 128 + ic0) * 32768 + l * 16 + (size_t)(js * 8) * 1024;
    const unsigned short* mb1 = mb0 + 32768;
    unsigned short* pw = &PA[w][0];
    int lrow = l >> 2, lch = (l & 3) * 8;
    int jb0 = js * 512;

    for (int t = 0; t < 8; t++) {
        int jb = jb0 + t * 64;
        // stage K and V tiles for this iter (chunk c = w*2+e)
#pragma unroll
        for (int e = 0; e < 2; e++) {
            int c = w * 2 + e, kk = c >> 2, r16 = (c & 3) * 16;
            GLDS16(Kh + (size_t)(jb + r16 + lrow) * 512 + kk * 32 + lch, Ks + kk * 2048 + r16 * 32);
            GLDS16(Vh + (size_t)(r16 + lrow) * 2048 + jb + kk * 32 + lch, Vs + kk * 2048 + r16 * 32);
        }
        // m fragments for tile t (drained by the same pre-barrier vmcnt)
        u16x8 mc[2][2];
        {
            size_t off = (size_t)t * 1024;
            mc[0][0] = *reinterpret_cast<const u16x8*>(mb0 + off);
            mc[0][1] = *reinterpret_cast<const u16x8*>(mb0 + off + 8);
            mc[1][0] = *reinterpret_cast<const u16x8*>(mb1 + off);
            mc[1][1] = *reinterpret_cast<const u16x8*>(mb1 + off + 8);
        }
        __syncthreads();   // staging complete
        // S^T = K.Q^T for both rc (K fragments read once)
        f32x4 S[2][4];
#pragma unroll
        for (int rc = 0; rc < 2; rc++)
#pragma unroll
            for (int mt = 0; mt < 4; mt++)
#pragma unroll
                for (int r = 0; r < 4; r++) S[rc][mt][r] = 0.f;
#pragma unroll
        for (int mt = 0; mt < 4; mt++) {
            bf16x8 kf0 = *reinterpret_cast<const bf16x8*>(Ks + (16 * mt + cl) * 32 + q * 8);
            bf16x8 kf1 = *reinterpret_cast<const bf16x8*>(Ks + 2048 + (16 * mt + cl) * 32 + q * 8);
#pragma unroll
            for (int rc = 0; rc < 2; rc++) {
                S[rc][mt] = __builtin_amdgcn_mfma_f32_16x16x32_bf16(kf0, qf[rc][0], S[rc][mt], 0, 0, 0);
                S[rc][mt] = __builtin_amdgcn_mfma_f32_16x16x32_bf16(kf1, qf[rc][1], S[rc][mt], 0, 0, 0);
            }
        }
        // per rc: p = exp2(S^T)*m -> PA (b64 writes)
#pragma unroll
        for (int rc = 0; rc < 2; rc++) {
#pragma unroll
            for (int mt = 0; mt < 4; mt++) {
                float p0 = fexp2(S[rc][mt][0]) * bu2f((mt < 2) ? mc[rc][0][mt * 4 + 0] : mc[rc][1][(mt - 2) * 4 + 0]);
                float p1 = fexp2(S[rc][mt][1]) * bu2f((mt < 2) ? mc[rc][0][mt * 4 + 1] : mc[rc][1][(mt - 2) * 4 + 1]);
                float p2 = fexp2(S[rc][mt][2]) * bu2f((mt < 2) ? mc[rc][0][mt * 4 + 2] : mc[rc][1][(mt - 2) * 4 + 2]);
                float p3 = fexp2(S[rc][mt][3]) * bu2f((mt < 2) ? mc[rc][0][mt * 4 + 3] : mc[rc][1][(mt - 2) * 4 + 3]);
                ushort4 o;
                o.x = f2bu(p0); o.y = f2bu(p1); o.z = f2bu(p2); o.w = f2bu(p3);
                *reinterpret_cast<ushort4*>(pw + rc * (16 * 72) + cl * 72 + 16 * mt + q * 4) = o;
            }
        }
        // O += P.V: per jc read both rc P-fragments, stream V fragments once
#pragma unroll
        for (int jc = 0; jc < 2; jc++) {
            bf16x8 pf0 = *reinterpret_cast<const bf16x8*>(pw + cl * 72 + jc * 32 + q * 8);
            bf16x8 pf1 = *reinterpret_cast<const bf16x8*>(pw + 16 * 72 + cl * 72 + jc * 32 + q * 8);
#pragma unroll
            for (int nt = 0; nt < 4; nt++) {
                bf16x8 vf = *reinterpret_cast<const bf16x8*>(Vs + jc * 2048 + (16 * nt + cl) * 32 + q * 8);
                O[0][nt] = __builtin_amdgcn_mfma_f32_16x16x32_bf16(pf0, vf, O[0][nt], 0, 0, 0);
                O[1][nt] = __builtin_amdgcn_mfma_f32_16x16x32_bf16(pf1, vf, O[1][nt], 0, 0, 0);
            }
            Osum[0] = __builtin_amdgcn_mfma_f32_16x16x32_bf16(pf0, ones, Osum[0], 0, 0, 0);
            Osum[1] = __builtin_amdgcn_mfma_f32_16x16x32_bf16(pf1, ones, Osum[1], 0, 0, 0);
        }
        __syncthreads();   // all waves done reading Ks/Vs before next staging
    }

    // epilogue: write bf16 partial O (lane-packed) + row sums
#pragma unroll
    for (int rc = 0; rc < 2; rc++) {
        size_t chunk = ((size_t)(bh * 128 + ic0 + rc)) * 4 + js;
        unsigned short* po = PO + chunk * 1024 + l * 16;
#pragma unroll
        for (int r = 0; r < 4; r++) {
            ushort4 o;
            o.x = f2bu(O[rc][0][r]); o.y = f2bu(O[rc][1][r]);
            o.z = f2bu(O[rc][2][r]); o.w = f2bu(O[rc][3][r]);
            *reinterpret_cast<ushort4*>(po + r * 4) = o;
        }
        if (cl == 0) {
#pragma unroll
            for (int r = 0; r < 4; r++)
                PL[chunk * 16 + q * 4 + r] = Osum[rc][r];
        }
    }
}

// ---------------- combine 4 j-quarters, normalize, residual ----------------
// 512 blocks (bh*32 + t64) x 256 thr; each block 4 row-chunks (64 rows).
__global__ void k_comb(const unsigned short* __restrict__ PO, const float* __restrict__ PL,
                       const float* __restrict__ x, float* __restrict__ out) {
    int blk = blockIdx.x;
    int t64 = blk & 31, bh = blk >> 5;
    int b = bh >> 3, h = bh & 7;
    int t = threadIdx.x;               // t = l*4 + r
    int l = t >> 2, r = t & 3, q = l >> 4, cl = l & 15;
#pragma unroll
    for (int w = 0; w < 4; w++) {
        int ic = t64 * 4 + w;
        size_t c0 = ((size_t)(bh * 128 + ic)) * 4;
        float o0 = 0.f, o1 = 0.f, o2 = 0.f, o3 = 0.f, lsum = 0.f;
#pragma unroll
        for (int js = 0; js < 4; js++) {
            ushort4 a = *reinterpret_cast<const ushort4*>(PO + (c0 + js) * 1024 + t * 4);
            o0 += bu2f(a.x); o1 += bu2f(a.y); o2 += bu2f(a.z); o3 += bu2f(a.w);
            lsum += PL[(c0 + js) * 16 + q * 4 + r];
        }
        float inv = 1.0f / lsum;
        size_t gro = (size_t)(b * 2048 + ic * 16 + q * 4 + r) * 512 + h * 64;
        out[gro + 0 * 16 + cl] = o0 * inv + x[gro + 0 * 16 + cl];
        out[gro + 1 * 16 + cl] = o1 * inv + x[gro + 1 * 16 + cl];
        out[gro + 2 * 16 + cl] = o2 * inv + x[gro + 2 * 16 + cl];
        out[gro + 3 * 16 + cl] = o3 * inv + x[gro + 3 * 16 + cl];
    }
}

extern "C" void kernel_launch(void* const* d_in, const int* in_sizes, int n_in,
                              void* d_out, int out_size, void* d_ws, size_t ws_size,
                              hipStream_t stream) {
    const float* x   = (const float*)d_in[0];
    const float* adj = (const float*)d_in[1];
    const float* Wq  = (const float*)d_in[2];
    const float* bq  = (const float*)d_in[3];
    const float* Wk  = (const float*)d_in[4];
    const float* bk  = (const float*)d_in[5];
    const float* Wv  = (const float*)d_in[6];
    const float* bv  = (const float*)d_in[7];
    const float* wg  = (const float*)d_in[8];
    // d_in[9] (b_g) unused: row-constant bias cancels in softmax
    float* out = (float*)d_out;
    char* ws = (char*)d_ws;
    unsigned short* Qs = (unsigned short*)(ws + OFF_QS);
    unsigned short* Kb = (unsigned short*)(ws + OFF_KB);
    unsigned short* Vt = (unsigned short*)(ws + OFF_VT);
    float* cv2 = (float*)(ws + OFF_CV);
    unsigned short* xb = (unsigned short*)(ws + OFF_XB);
    unsigned short* wt = (unsigned short*)(ws + OFF_WT);
    unsigned short* mqp = (unsigned short*)(ws + OFF_MQ);
    unsigned short* PO = (unsigned short*)(ws + OFF_PO);
    float* PL = (float*)(ws + OFF_PL);

    k_prepwt<<<1216, 256, 0, stream>>>(x, wg, Wq, Wk, Wv, xb, cv2, wt);
    k_mid<<<8960, 256, 0, stream>>>(adj, cv2, mqp, xb, wt, bq, bk, bv, Qs, Kb, Vt);
    k_attn<<<1024, 256, 0, stream>>>(Qs, Kb, Vt, mqp, PO, PL);
    k_comb<<<512, 256, 0, stream>>>(PO, PL, x, out);
}